// Round 13
// baseline (104.794 us; speedup 1.0000x reference)
//
#include <hip/hip_runtime.h>
#include <hip/hip_bf16.h>
#include <cstdint>

typedef __attribute__((ext_vector_type(8))) short sh8;    // 8 x bf16 bits
typedef __attribute__((ext_vector_type(4))) float f4;     // 16x16 MFMA acc
typedef __attribute__((ext_vector_type(16))) float f16v;  // 32x32 MFMA acc

#define T_SEQ 4096
#define DIMN  1024
#define NH    8
#define HDIM  128
#define NQKV  3072
#define ATTN_SCALE 0.12f

__device__ __forceinline__ ushort f2bf(float x) {
  __hip_bfloat16 b = __float2bfloat16(x);
  return *reinterpret_cast<ushort*>(&b);
}
__device__ __forceinline__ float bf2f(ushort u) {
  uint v = ((uint)u) << 16;
  float f;
  __builtin_memcpy(&f, &v, 4);
  return f;
}

#define GLDS16(g, l) \
  __builtin_amdgcn_global_load_lds((const __attribute__((address_space(1))) void*)(g), \
                                   (__attribute__((address_space(3))) void*)(l), 16, 0, 0)

template <int N>
__device__ __forceinline__ void wait_vmcnt() {
  if constexpr (N == 0)      asm volatile("s_waitcnt vmcnt(0)" ::: "memory");
  else if constexpr (N == 4) asm volatile("s_waitcnt vmcnt(4)" ::: "memory");
  else if constexpr (N == 8) asm volatile("s_waitcnt vmcnt(8)" ::: "memory");
  __builtin_amdgcn_sched_barrier(0);
}
#define BAR __builtin_amdgcn_s_barrier()

// ---------------- prep: 3 fp32->bf16 converts + doc_start ----------------
__global__ __launch_bounds__(256) void k_prep(const float* __restrict__ x,
                                              const float* __restrict__ qw,
                                              const float* __restrict__ cw,
                                              ushort* __restrict__ xb, ushort* __restrict__ wb,
                                              ushort* __restrict__ cbuf,
                                              const int* __restrict__ docs, int* __restrict__ dstart) {
  const int b = blockIdx.x;
  if (b < 8192) {
    const int i = b * 256 + threadIdx.x;
    const float* src;
    ushort* dst;
    int j;
    if (i < 1048576)       { src = x;  dst = xb;   j = i; }
    else if (i < 1835008)  { src = qw; dst = wb;   j = i - 1048576; }
    else                   { src = cw; dst = cbuf; j = i - 1835008; }
    float4 v = reinterpret_cast<const float4*>(src)[j];
    ushort4 o;
    o.x = f2bf(v.x); o.y = f2bf(v.y); o.z = f2bf(v.z); o.w = f2bf(v.w);
    reinterpret_cast<ushort4*>(dst)[j] = o;
  } else {
    const int i = (b - 8192) * 256 + threadIdx.x;
    if (i < T_SEQ) {
      int d = docs[i];
      int lo = 0, hi = i;
      while (lo < hi) { int mid = (lo + hi) >> 1; if (docs[mid] < d) lo = mid + 1; else hi = mid; }
      dstart[i] = lo;
    }
  }
}

// ---------------- QKV GEMM: C[M][N] = A[M][K]*B[N][K]^T, 32x32x16 MFMA ----------------
// R10 config: BM=128 BN=384 BK=64, grid 256 (1/CU), 8 waves (2M x 4N), 64x96/wave.
// Row-major 128B LDS rows + XOR-8 chunk swizzle; coalesced staging.
// R12 change: SINGLE barrier per K-tile (mid-barrier removed — stage writes buf^1,
// reads are from buf; end-of-tile vmcnt(0)+BAR alone guarantees t+1 landed).
__global__ __launch_bounds__(512, 2) void k_gemm32(const ushort* __restrict__ A,
                                                   const ushort* __restrict__ B,
                                                   ushort* __restrict__ C,
                                                   int N, int K) {
  __shared__ ushort lds[2][512 * 64];   // 128KB
  const int tid = threadIdx.x;
  const int lane = tid & 63;
  const int w = tid >> 6;
  const int l5 = lane >> 5;        // k-subgroup (0/1)
  const int lr32 = lane & 31;      // row/col within 32-frag
  const int wave_m = w >> 2, wave_n = w & 3;

  // XCD-aware bijective remap: XCD x -> 4 m-panels x its private 384-col B slice
  const int bid = blockIdx.x;
  const int s = (bid & 7) * 32 + (bid >> 3);            // 0..255
  const int m0 = ((s >> 5) * 4 + ((s >> 3) & 3)) * 128; // 32 m-tiles
  const int n0 = (s & 7) * 384;                         // 8 n-tiles

  f16v acc[2][3];
#pragma unroll
  for (int i = 0; i < 2; ++i)
#pragma unroll
    for (int j = 0; j < 3; ++j)
#pragma unroll
      for (int r = 0; r < 16; ++r) acc[i][j][r] = 0.f;

  const int NT = K >> 6;

  // stage 4 units (unit = 64 rows x 8 chunks of 16B; 1 load/thread/unit)
  auto STAGE4 = [&](int buf, int t, int ug) {
    const int k0 = t << 6;
#pragma unroll
    for (int uu = 0; uu < 4; ++uu) {
      const int u = ug * 4 + uu;
      const int row = u * 64 + (tid >> 3);              // 0..511
      const int c = (tid & 7) ^ (row & 7);              // inverse-swizzled source chunk
      const ushort* src = (u < 2) ? (A + (size_t)(m0 + row) * K + k0 + c * 8)
                                  : (B + (size_t)(n0 + row - 128) * K + k0 + c * 8);
      GLDS16(src, (char*)&lds[buf][0] + u * 8192 + w * 1024);  // + lane*16 by HW
    }
  };

  STAGE4(0, 0, 0); STAGE4(0, 0, 1);
  wait_vmcnt<0>();
  BAR;

  int cur = 0;
  for (int t = 0; t < NT; ++t) {
    const bool more = (t + 1) < NT;
    const char* bb = (const char*)&lds[cur][0];

#define RD_FRAGS(ks, a, b)                                                        \
    _Pragma("unroll") for (int mt = 0; mt < 2; ++mt) {                            \
      const int row = wave_m * 64 + mt * 32 + lr32;                               \
      a[mt] = *(const sh8*)(bb + row * 128 + ((((ks) * 2 + l5) ^ (row & 7)) * 16));\
    }                                                                             \
    _Pragma("unroll") for (int nt = 0; nt < 3; ++nt) {                            \
      const int row = 128 + wave_n * 96 + nt * 32 + lr32;                         \
      b[nt] = *(const sh8*)(bb + row * 128 + ((((ks) * 2 + l5) ^ (row & 7)) * 16));\
    }

#define MFMA6(a, b)                                                               \
    __builtin_amdgcn_s_setprio(1);                                                \
    _Pragma("unroll") for (int mt = 0; mt < 2; ++mt)                              \
    _Pragma("unroll") for (int nt = 0; nt < 3; ++nt)                              \
      acc[mt][nt] = __builtin_amdgcn_mfma_f32_32x32x16_bf16(a[mt], b[nt],         \
                                                            acc[mt][nt], 0, 0, 0);\
    __builtin_amdgcn_s_setprio(0);

    {
      sh8 a[2], b[3];
      RD_FRAGS(0, a, b)
      if (more) STAGE4(cur ^ 1, t + 1, 0);
      MFMA6(a, b)
    }
    {
      sh8 a[2], b[3];
      RD_FRAGS(1, a, b)
      if (more) STAGE4(cur ^ 1, t + 1, 1);
      MFMA6(a, b)
    }
    {
      sh8 a[2], b[3];
      RD_FRAGS(2, a, b)
      MFMA6(a, b)
    }
    {
      sh8 a[2], b[3];
      RD_FRAGS(3, a, b)
      MFMA6(a, b)
    }
    if (more) wait_vmcnt<0>();   // all of t+1's loads retired (per-wave own portion)
    BAR;                         // all waves done reading cur + staging -> flip
    cur ^= 1;
  }
#undef RD_FRAGS
#undef MFMA6

#pragma unroll
  for (int mt = 0; mt < 2; ++mt)
#pragma unroll
    for (int nt = 0; nt < 3; ++nt) {
      const int gcol = n0 + wave_n * 96 + nt * 32 + lr32;
#pragma unroll
      for (int r = 0; r < 16; ++r) {
        const int grow = m0 + wave_m * 64 + mt * 32 + (r & 3) + 8 * (r >> 2) + 4 * l5;
        C[(size_t)grow * N + gcol] = f2bf(acc[mt][nt][r]);
      }
    }
}

// ---------------- proj GEMM: 128x128, BK=32, 3-buffer, 32x32x16 (R6 structure) ----------------
__global__ __launch_bounds__(256) void k_gemm2(const ushort* __restrict__ A,
                                               const ushort* __restrict__ B,
                                               float* __restrict__ C,
                                               int N, int K, int gx) {
  constexpr int BM = 128, BN = 128;
  constexpr int CHA = BM * 4;
  constexpr int TILEB = (BM + BN) * 64;    // 16KB

  __shared__ __attribute__((aligned(16))) char lds[3 * TILEB];

  const int tid = threadIdx.x;
  const int lane = tid & 63;
  const int w = tid >> 6;
  const int l5 = lane >> 5;
  const int lr32 = lane & 31;
  const int wm = w >> 1, wn = w & 1;

  const int nwg = gridDim.x;
  const int nb = (blockIdx.x & 7) * (nwg >> 3) + (blockIdx.x >> 3);
  const int m0 = (nb / gx) * BM;
  const int n0 = (nb % gx) * BN;

  f16v acc[2][2];
#pragma unroll
  for (int i = 0; i < 2; ++i)
#pragma unroll
    for (int j = 0; j < 2; ++j)
#pragma unroll
      for (int r = 0; r < 16; ++r) acc[i][j][r] = 0.f;

  const int NT = K >> 5;

  auto STAGE = [&](int t, int buf) {
    const int k0 = t << 5;
#pragma unroll
    for (int l = 0; l < 4; ++l) {
      const int cb = (l * 4 + w) * 64;
      const int ch = cb + lane;
      const ushort* src;
      if (ch < CHA) {
        const int row = ch >> 2;
        const int cs = (ch & 3) ^ ((row >> 1) & 3);
        src = A + (size_t)(m0 + row) * K + k0 + cs * 8;
      } else {
        const int c2 = ch - CHA;
        const int row = c2 >> 2;
        const int cs = (c2 & 3) ^ ((row >> 1) & 3);
        src = B + (size_t)(n0 + row) * K + k0 + cs * 8;
      }
      GLDS16(src, lds + buf * TILEB + cb * 16);
    }
  };

  STAGE(0, 0);
  STAGE(1, 1);
  wait_vmcnt<4>();
  BAR;

  int bufc = 0;
  for (int t = 0; t < NT; ++t) {
    const bool more = (t + 2) < NT;
    if (more) STAGE(t + 2, bufc == 0 ? 2 : (bufc == 1 ? 0 : 1));

    const char* bb = lds + bufc * TILEB;
#pragma unroll
    for (int ks = 0; ks < 2; ++ks) {
      sh8 a[2], b[2];
#pragma unroll
      for (int mt = 0; mt < 2; ++mt) {
        const int row = wm * 64 + mt * 32 + lr32;
        a[mt] = *(const sh8*)(bb + row * 64 + (((ks * 2 + l5) ^ ((row >> 1) & 3)) * 16));
      }
#pragma unroll
      for (int nt = 0; nt < 2; ++nt) {
        const int row = wn * 64 + nt * 32 + lr32;
        b[nt] = *(const sh8*)(bb + BM * 64 + row * 64 + (((ks * 2 + l5) ^ ((row >> 1) & 3)) * 16));
      }
      __builtin_amdgcn_s_setprio(1);
#pragma unroll
      for (int mt = 0; mt < 2; ++mt)
#pragma unroll
        for (int nt = 0; nt < 2; ++nt)
          acc[mt][nt] = __builtin_amdgcn_mfma_f32_32x32x16_bf16(a[mt], b[nt], acc[mt][nt], 0, 0, 0);
      __builtin_amdgcn_s_setprio(0);
    }

    if (more) wait_vmcnt<4>();
    else      wait_vmcnt<0>();
    BAR;
    bufc = bufc == 2 ? 0 : bufc + 1;
  }

#pragma unroll
  for (int mt = 0; mt < 2; ++mt)
#pragma unroll
    for (int nt = 0; nt < 2; ++nt) {
      const int gcol = n0 + wn * 64 + nt * 32 + lr32;
#pragma unroll
      for (int r = 0; r < 16; ++r) {
        const int grow = m0 + wm * 64 + mt * 32 + (r & 3) + 8 * (r >> 2) + 4 * l5;
        __builtin_nontemporal_store(acc[mt][nt][r], &C[(size_t)grow * N + gcol]);
      }
    }
}

// ---------------- fused RMSNorm + rotary + V-mix (4 (t,h) pairs / block) ----------------
__global__ __launch_bounds__(256) void k_fuse(const ushort* __restrict__ qkvb,
                                              const float* __restrict__ ve,
                                              const float* __restrict__ lam,
                                              ushort* __restrict__ qh, ushort* __restrict__ kh,
                                              ushort* __restrict__ vh) {
  const int pair = blockIdx.x * 4 + (threadIdx.x >> 6);
  const int t = pair >> 3, h = pair & 7;
  const int l = threadIdx.x & 63;
  const ushort* base = qkvb + (size_t)t * NQKV + h * HDIM + 2 * l;
  uint qu = *reinterpret_cast<const uint*>(base);
  uint ku = *reinterpret_cast<const uint*>(base + 1024);
  uint vu = *reinterpret_cast<const uint*>(base + 2048);
  float q0 = bf2f((ushort)qu), q1 = bf2f((ushort)(qu >> 16));
  float k0 = bf2f((ushort)ku), k1 = bf2f((ushort)(ku >> 16));
  float v0 = bf2f((ushort)vu), v1 = bf2f((ushort)(vu >> 16));
  float sq = q0 * q0 + q1 * q1, sk = k0 * k0 + k1 * k1;
#pragma unroll
  for (int m = 1; m < 64; m <<= 1) { sq += __shfl_xor(sq, m); sk += __shfl_xor(sk, m); }
  const float eps = 1.1920928955078125e-07f;
  float rq = rsqrtf(sq * (1.f / 128.f) + eps);
  float rk = rsqrtf(sk * (1.f / 128.f) + eps);
  q0 *= rq; q1 *= rq; k0 *= rk; k1 *= rk;
  float c0 = 1.f, s0 = 0.f, c1 = 1.f, s1 = 0.f;
  if ((l & 31) < 16) {
    const int f0 = 2 * (l & 31);
    float fr0 = exp2f(-10.f * (float)f0 * (1.f / 31.f));
    float fr1 = exp2f(-10.f * (float)(f0 + 1) * (1.f / 31.f));
    sincosf((float)t * fr0, &s0, &c0);
    sincosf((float)t * fr1, &s1, &c1);
  }
  float qx0 = __shfl_xor(q0, 32), qx1 = __shfl_xor(q1, 32);
  float kx0 = __shfl_xor(k0, 32), kx1 = __shfl_xor(k1, 32);
  const float sgn = (l < 32) ? 1.f : -1.f;
  float qr0 = q0 * c0 + sgn * qx0 * s0;
  float qr1 = q1 * c1 + sgn * qx1 * s1;
  float kr0 = k0 * c0 + sgn * kx0 * s0;
  float kr1 = k1 * c1 + sgn * kx1 * s1;
  const float l0 = lam[0], l1 = lam[1];
  float2 vev = *reinterpret_cast<const float2*>(ve + (size_t)t * DIMN + h * HDIM + 2 * l);
  float vr0 = l0 * v0 + l1 * vev.x;
  float vr1 = l0 * v1 + l1 * vev.y;
  const size_t o = ((size_t)h * T_SEQ + t) * HDIM + 2 * l;
  *reinterpret_cast<uint*>(qh + o) = (uint)f2bf(qr0) | ((uint)f2bf(qr1) << 16);
  *reinterpret_cast<uint*>(kh + o) = (uint)f2bf(kr0) | ((uint)f2bf(kr1) << 16);
  *reinterpret_cast<uint*>(vh + o) = (uint)f2bf(vr0) | ((uint)f2bf(vr1) << 16);
}

// ---------------- V transpose: vh[h][t][d] -> vt[h][d][t] ----------------
__global__ __launch_bounds__(256) void k_vt(const ushort* __restrict__ vh, ushort* __restrict__ vt) {
  const int tb = blockIdx.x, db = blockIdx.y, h = blockIdx.z;
  __shared__ ushort L[64][68];
  const int tid = threadIdx.x;
  const int t0 = tb * 64, d0 = db * 64;
  const size_t ib = ((size_t)h * T_SEQ + t0) * HDIM + d0;
#pragma unroll
  for (int p = 0; p < 4; ++p) {
    const int row = p * 16 + (tid >> 4);
    const int c4 = (tid & 15) * 4;
    ushort4 v = *reinterpret_cast<const ushort4*>(vh + ib + (size_t)row * HDIM + c4);
    *reinterpret_cast<ushort4*>(&L[row][c4]) = v;
  }
  __syncthreads();
  const size_t ob = ((size_t)h * HDIM + d0) * T_SEQ + t0;
#pragma unroll
  for (int p = 0; p < 4; ++p) {
    const int drow = p * 16 + (tid >> 4);
    const int t4 = (tid & 15) * 4;
    ushort4 v;
    v.x = L[t4 + 0][drow]; v.y = L[t4 + 1][drow];
    v.z = L[t4 + 2][drow]; v.w = L[t4 + 3][drow];
    *reinterpret_cast<ushort4*>(vt + ob + (size_t)drow * T_SEQ + t4) = v;
  }
}

// ---------------- flash attention: 4 waves, 64 q-rows, LDS-staged KV ----------------
// LPT: largest-span q-blocks dispatched first (qb reversed); h->XCD pinning kept.
__global__ __launch_bounds__(256) void k_attn(const ushort* __restrict__ qh,
                                              const ushort* __restrict__ kh,
                                              const ushort* __restrict__ vt,
                                              const int* __restrict__ doc_start,
                                              ushort* __restrict__ y) {
  const int h  = blockIdx.x;
  const int qb = gridDim.y - 1 - blockIdx.y;   // LPT: big blocks first
  const int q0 = qb * 64;
  const int tid  = threadIdx.x;
  const int wave = tid >> 6;
  const int lane = tid & 63;
  const int lr = lane & 15, lg = lane >> 4;

  __shared__ ushort Ks[2][64 * 128];
  __shared__ ushort Vs[2][128 * 64];
  __shared__ ushort Ps[4][16 * 64];

  const ushort* Kg = kh + (size_t)h * T_SEQ * HDIM;
  const ushort* Vg = vt + (size_t)h * HDIM * T_SEQ;

  const int i_me = q0 + wave * 16 + lr;
  sh8 qf[4];
  {
    const ushort* qp = qh + ((size_t)h * T_SEQ + i_me) * HDIM + lg * 8;
#pragma unroll
    for (int c = 0; c < 4; ++c) qf[c] = *reinterpret_cast<const sh8*>(qp + c * 32);
  }
  const int ds_me = doc_start[i_me];
  const int ds_hi = doc_start[q0 + 63];
  const int kb0   = doc_start[q0] >> 6;

  const f4 fzero = {0.f, 0.f, 0.f, 0.f};
  f4 o_acc[8];
#pragma unroll
  for (int i = 0; i < 8; ++i) o_acc[i] = fzero;
  float m_me = -1e30f, l_me = 0.f;

  auto STAGE = [&](int b, int k0) {
#pragma unroll
    for (int p = 0; p < 4; ++p) {
      const int c = p * 256 + tid;
      const int row = c >> 4, cc = c & 15;
      GLDS16(Kg + (size_t)(k0 + row) * HDIM + (cc ^ (row & 7)) * 8,
             &Ks[b][(p * 256 + wave * 64) * 8]);
    }
#pragma unroll
    for (int p = 0; p < 4; ++p) {
      const int c = p * 256 + tid;
      const int d = c >> 3, cc = c & 7;
      GLDS16(Vg + (size_t)d * T_SEQ + k0 + (cc ^ (d & 7)) * 8,
             &Vs[b][(p * 256 + wave * 64) * 8]);
    }
  };

  int cur = 0;
  STAGE(0, kb0 * 64);

  const int sw = (lr & 7) << 4;

  for (int kb = kb0; kb <= qb; ++kb) {
    const int k0 = kb * 64;
    __syncthreads();
    if (kb < qb) STAGE(cur ^ 1, k0 + 64);

    const char* Kb = (const char*)&Ks[cur][0];
    const char* Vb = (const char*)&Vs[cur][0];
    char* Pw = (char*)&Ps[wave][0];

    f4 sacc[4];
#pragma unroll
    for (int jt = 0; jt < 4; ++jt) sacc[jt] = fzero;
#pragma unroll
    for (int jt = 0; jt < 4; ++jt)
#pragma unroll
      for (int c = 0; c < 4; ++c) {
        sh8 kf = *reinterpret_cast<const sh8*>(Kb + (jt * 16 + lr) * 256 + ((c * 64 + lg * 16) ^ sw));
        sacc[jt] = __builtin_amdgcn_mfma_f32_16x16x32_bf16(kf, qf[c], sacc[jt], 0, 0, 0);
      }

    const bool fullblk = (kb < qb) && (ds_hi <= k0);
    float p[4][4];
#pragma unroll
    for (int jt = 0; jt < 4; ++jt)
#pragma unroll
      for (int r = 0; r < 4; ++r) {
        float s = sacc[jt][r] * ATTN_SCALE;
        const int j = k0 + jt * 16 + lg * 4 + r;
        bool valid = fullblk || ((j <= i_me) && (j >= ds_me));
        p[jt][r] = valid ? s : -1e30f;
      }
    float tm = -1e30f;
#pragma unroll
    for (int jt = 0; jt < 4; ++jt) {
      float a = fmaxf(p[jt][0], p[jt][1]), b = fmaxf(p[jt][2], p[jt][3]);
      tm = fmaxf(tm, fmaxf(a, b));
    }
    tm = fmaxf(tm, __shfl_xor(tm, 16));
    tm = fmaxf(tm, __shfl_xor(tm, 32));
    const float mnew = fmaxf(m_me, tm);
    const float sc = __expf(m_me - mnew);
    m_me = mnew;
    float rs = 0.f;
#pragma unroll
    for (int jt = 0; jt < 4; ++jt)
#pragma unroll
      for (int r = 0; r < 4; ++r) {
        float pv = __expf(p[jt][r] - mnew);
        p[jt][r] = pv;
        rs += pv;
      }
    rs += __shfl_xor(rs, 16);
    rs += __shfl_xor(rs, 32);
    l_me = l_me * sc + rs;

#pragma unroll
    for (int jt = 0; jt < 4; ++jt) {
      uint2 u;
      u.x = (uint)f2bf(p[jt][0]) | ((uint)f2bf(p[jt][1]) << 16);
      u.y = (uint)f2bf(p[jt][2]) | ((uint)f2bf(p[jt][3]) << 16);
      *reinterpret_cast<uint2*>(Pw + lr * 128 + ((jt * 32 + lg * 8) ^ sw)) = u;
    }

    float sco[4];
#pragma unroll
    for (int rr = 0; rr < 4; ++rr) sco[rr] = __shfl(sc, lg * 4 + rr);
#pragma unroll
    for (int dt = 0; dt < 8; ++dt)
#pragma unroll
      for (int rr = 0; rr < 4; ++rr) o_acc[dt][rr] *= sco[rr];

#pragma unroll
    for (int ks = 0; ks < 2; ++ks) {
      sh8 pa = *reinterpret_cast<const sh8*>(Pw + lr * 128 + ((ks * 64 + lg * 16) ^ sw));
#pragma unroll
      for (int dt = 0; dt < 8; ++dt) {
        sh8 vf = *reinterpret_cast<const sh8*>(Vb + (dt * 16 + lr) * 128 + ((ks * 64 + lg * 16) ^ sw));
        o_acc[dt] = __builtin_amdgcn_mfma_f32_16x16x32_bf16(pa, vf, o_acc[dt], 0, 0, 0);
      }
    }

    __builtin_amdgcn_s_barrier();
    cur ^= 1;
  }

  float lo[4];
#pragma unroll
  for (int rr = 0; rr < 4; ++rr) lo[rr] = __shfl(l_me, lg * 4 + rr);
#pragma unroll
  for (int dt = 0; dt < 8; ++dt)
#pragma unroll
    for (int rr = 0; rr < 4; ++rr) {
      const int trow = q0 + wave * 16 + lg * 4 + rr;
      y[(size_t)trow * DIMN + h * HDIM + dt * 16 + lr] = f2bf(o_acc[dt][rr] / lo[rr]);
    }
}

extern "C" void kernel_launch(void* const* d_in, const int* in_sizes, int n_in,
                              void* d_out, int out_size, void* d_ws, size_t ws_size,
                              hipStream_t stream) {
  const float* x    = (const float*)d_in[0];
  const float* ve   = (const float*)d_in[1];
  const float* qkvw = (const float*)d_in[2];
  const float* lam  = (const float*)d_in[3];
  const float* cpw  = (const float*)d_in[4];
  const int*   docs = (const int*)d_in[5];
  float* out = (float*)d_out;
  char* ws = (char*)d_ws;

  ushort* qkvb = (ushort*)(ws);                    // 24MB  [0,24)
  ushort* xb   = (ushort*)(ws + (24ull << 20));    // 8MB   [24,32)
  ushort* wb   = (ushort*)(ws + (32ull << 20));    // 6MB   [32,38)
  ushort* cb   = (ushort*)(ws + (38ull << 20));    // 2MB   [38,40)
  ushort* qh   = (ushort*)(ws + (40ull << 20));    // 8MB   [40,48)
  ushort* kh   = (ushort*)(ws + (48ull << 20));    // 8MB   [48,56)
  ushort* vh   = (ushort*)(ws + (56ull << 20));    // 8MB   [56,64)
  ushort* vt   = (ushort*)(ws + (64ull << 20));    // 8MB   [64,72)
  ushort* yb   = (ushort*)(ws + (72ull << 20));    // 8MB   [72,80)
  int*  dstart = (int*)(ws + (80ull << 20));       // 16KB

  k_prep<<<8192 + 16, 256, 0, stream>>>(x, qkvw, cpw, xb, wb, cb, docs, dstart);

  // QKV: M=4096, N=3072, K=1024 — 128x384 tiles, grid 32x8 = 256 = 1/CU
  k_gemm32<<<256, 512, 0, stream>>>(xb, wb, qkvb, NQKV, DIMN);

  k_fuse<<<T_SEQ * NH / 4, 256, 0, stream>>>(qkvb, ve, lam, qh, kh, vh);
  k_vt<<<dim3(T_SEQ / 64, HDIM / 64, NH), 256, 0, stream>>>(vh, vt);

  k_attn<<<dim3(NH, T_SEQ / 64), 256, 0, stream>>>(qh, kh, vt, dstart, yb);

  // proj: M=4096, N=1024, K=1024 — 128x128 tile, grid 32x8=256 (%8==0)
  k_gemm2<<<256, 256, 0, stream>>>(yb, cb, out, DIMN, DIMN, DIMN / 128);
}

// Round 14
// 100.591 us; speedup vs baseline: 1.0418x; 1.0418x over previous
//
#include <hip/hip_runtime.h>
#include <hip/hip_bf16.h>
#include <cstdint>

typedef __attribute__((ext_vector_type(8))) short sh8;    // 8 x bf16 bits
typedef __attribute__((ext_vector_type(4))) float f4;     // 16x16 MFMA acc
typedef __attribute__((ext_vector_type(16))) float f16v;  // 32x32 MFMA acc

#define T_SEQ 4096
#define DIMN  1024
#define NH    8
#define HDIM  128
#define NQKV  3072
#define ATTN_SCALE 0.12f

__device__ __forceinline__ ushort f2bf(float x) {
  __hip_bfloat16 b = __float2bfloat16(x);
  return *reinterpret_cast<ushort*>(&b);
}
__device__ __forceinline__ float bf2f(ushort u) {
  uint v = ((uint)u) << 16;
  float f;
  __builtin_memcpy(&f, &v, 4);
  return f;
}

#define GLDS16(g, l) \
  __builtin_amdgcn_global_load_lds((const __attribute__((address_space(1))) void*)(g), \
                                   (__attribute__((address_space(3))) void*)(l), 16, 0, 0)

template <int N>
__device__ __forceinline__ void wait_vmcnt() {
  if constexpr (N == 0)      asm volatile("s_waitcnt vmcnt(0)" ::: "memory");
  else if constexpr (N == 4) asm volatile("s_waitcnt vmcnt(4)" ::: "memory");
  else if constexpr (N == 8) asm volatile("s_waitcnt vmcnt(8)" ::: "memory");
  __builtin_amdgcn_sched_barrier(0);
}
#define BAR __builtin_amdgcn_s_barrier()

// ---------------- prep: 3 fp32->bf16 converts + doc_start ----------------
__global__ __launch_bounds__(256) void k_prep(const float* __restrict__ x,
                                              const float* __restrict__ qw,
                                              const float* __restrict__ cw,
                                              ushort* __restrict__ xb, ushort* __restrict__ wb,
                                              ushort* __restrict__ cbuf,
                                              const int* __restrict__ docs, int* __restrict__ dstart) {
  const int b = blockIdx.x;
  if (b < 8192) {
    const int i = b * 256 + threadIdx.x;
    const float* src;
    ushort* dst;
    int j;
    if (i < 1048576)       { src = x;  dst = xb;   j = i; }
    else if (i < 1835008)  { src = qw; dst = wb;   j = i - 1048576; }
    else                   { src = cw; dst = cbuf; j = i - 1835008; }
    float4 v = reinterpret_cast<const float4*>(src)[j];
    ushort4 o;
    o.x = f2bf(v.x); o.y = f2bf(v.y); o.z = f2bf(v.z); o.w = f2bf(v.w);
    reinterpret_cast<ushort4*>(dst)[j] = o;
  } else {
    const int i = (b - 8192) * 256 + threadIdx.x;
    if (i < T_SEQ) {
      int d = docs[i];
      int lo = 0, hi = i;
      while (lo < hi) { int mid = (lo + hi) >> 1; if (docs[mid] < d) lo = mid + 1; else hi = mid; }
      dstart[i] = lo;
    }
  }
}

// ---------------- QKV GEMM: C[M][N] = A[M][K]*B[N][K]^T, 32x32x16 MFMA ----------------
// R6/R10-proven config: BM=128 BN=384 BK=64, grid 256 (1/CU), 8 waves (2M x 4N), 64x96/wave.
// Row-major 128B LDS rows + XOR-8 chunk swizzle; coalesced staging.
// Schedule: {RD(0)+STAGE(ug0)+MFMA, RD(1)+STAGE(ug1)+MFMA, BAR, RD(2)+MFMA,
//            vmcnt(4), RD(3)+MFMA, vmcnt(0), BAR}.  (Mid-barrier is load-bearing:
//            it keeps waves phase-locked so stage-issues complete early — R13 A/B.)
__global__ __launch_bounds__(512, 2) void k_gemm32(const ushort* __restrict__ A,
                                                   const ushort* __restrict__ B,
                                                   ushort* __restrict__ C,
                                                   int N, int K) {
  __shared__ ushort lds[2][512 * 64];   // 128KB
  const int tid = threadIdx.x;
  const int lane = tid & 63;
  const int w = tid >> 6;
  const int l5 = lane >> 5;        // k-subgroup (0/1)
  const int lr32 = lane & 31;      // row/col within 32-frag
  const int wave_m = w >> 2, wave_n = w & 3;

  // XCD-aware bijective remap: XCD x -> 4 m-panels x its private 384-col B slice
  const int bid = blockIdx.x;
  const int s = (bid & 7) * 32 + (bid >> 3);            // 0..255
  const int m0 = ((s >> 5) * 4 + ((s >> 3) & 3)) * 128; // 32 m-tiles
  const int n0 = (s & 7) * 384;                         // 8 n-tiles

  f16v acc[2][3];
#pragma unroll
  for (int i = 0; i < 2; ++i)
#pragma unroll
    for (int j = 0; j < 3; ++j)
#pragma unroll
      for (int r = 0; r < 16; ++r) acc[i][j][r] = 0.f;

  const int NT = K >> 6;

  // stage 4 units (unit = 64 rows x 8 chunks of 16B; 1 load/thread/unit)
  auto STAGE4 = [&](int buf, int t, int ug) {
    const int k0 = t << 6;
#pragma unroll
    for (int uu = 0; uu < 4; ++uu) {
      const int u = ug * 4 + uu;
      const int row = u * 64 + (tid >> 3);              // 0..511
      const int c = (tid & 7) ^ (row & 7);              // inverse-swizzled source chunk
      const ushort* src = (u < 2) ? (A + (size_t)(m0 + row) * K + k0 + c * 8)
                                  : (B + (size_t)(n0 + row - 128) * K + k0 + c * 8);
      GLDS16(src, (char*)&lds[buf][0] + u * 8192 + w * 1024);  // + lane*16 by HW
    }
  };

  STAGE4(0, 0, 0); STAGE4(0, 0, 1);
  wait_vmcnt<0>();
  BAR;

  int cur = 0;
  for (int t = 0; t < NT; ++t) {
    const bool more = (t + 1) < NT;
    const char* bb = (const char*)&lds[cur][0];

#define RD_FRAGS(ks, a, b)                                                        \
    _Pragma("unroll") for (int mt = 0; mt < 2; ++mt) {                            \
      const int row = wave_m * 64 + mt * 32 + lr32;                               \
      a[mt] = *(const sh8*)(bb + row * 128 + ((((ks) * 2 + l5) ^ (row & 7)) * 16));\
    }                                                                             \
    _Pragma("unroll") for (int nt = 0; nt < 3; ++nt) {                            \
      const int row = 128 + wave_n * 96 + nt * 32 + lr32;                         \
      b[nt] = *(const sh8*)(bb + row * 128 + ((((ks) * 2 + l5) ^ (row & 7)) * 16));\
    }

#define MFMA6(a, b)                                                               \
    __builtin_amdgcn_s_setprio(1);                                                \
    _Pragma("unroll") for (int mt = 0; mt < 2; ++mt)                              \
    _Pragma("unroll") for (int nt = 0; nt < 3; ++nt)                              \
      acc[mt][nt] = __builtin_amdgcn_mfma_f32_32x32x16_bf16(a[mt], b[nt],         \
                                                            acc[mt][nt], 0, 0, 0);\
    __builtin_amdgcn_s_setprio(0);

    {
      sh8 a[2], b[3];
      RD_FRAGS(0, a, b)
      if (more) STAGE4(cur ^ 1, t + 1, 0);
      MFMA6(a, b)
    }
    {
      sh8 a[2], b[3];
      RD_FRAGS(1, a, b)
      if (more) STAGE4(cur ^ 1, t + 1, 1);
      MFMA6(a, b)
    }
    BAR;  // mid lockstep
    {
      sh8 a[2], b[3];
      RD_FRAGS(2, a, b)
      MFMA6(a, b)
    }
    if (more) wait_vmcnt<4>();   // units 0-3 of t+1
    {
      sh8 a[2], b[3];
      RD_FRAGS(3, a, b)
      MFMA6(a, b)
    }
    if (more) wait_vmcnt<0>();   // units 4-7 of t+1
    BAR;                         // buf flip
    cur ^= 1;
  }
#undef RD_FRAGS
#undef MFMA6

#pragma unroll
  for (int mt = 0; mt < 2; ++mt)
#pragma unroll
    for (int nt = 0; nt < 3; ++nt) {
      const int gcol = n0 + wave_n * 96 + nt * 32 + lr32;
#pragma unroll
      for (int r = 0; r < 16; ++r) {
        const int grow = m0 + wave_m * 64 + mt * 32 + (r & 3) + 8 * (r >> 2) + 4 * l5;
        C[(size_t)grow * N + gcol] = f2bf(acc[mt][nt][r]);
      }
    }
}

// ---------------- proj GEMM: 128x128, BK=32, 3-buffer, 32x32x16 (R6 structure) ----------------
__global__ __launch_bounds__(256) void k_gemm2(const ushort* __restrict__ A,
                                               const ushort* __restrict__ B,
                                               float* __restrict__ C,
                                               int N, int K, int gx) {
  constexpr int BM = 128, BN = 128;
  constexpr int CHA = BM * 4;
  constexpr int TILEB = (BM + BN) * 64;    // 16KB

  __shared__ __attribute__((aligned(16))) char lds[3 * TILEB];

  const int tid = threadIdx.x;
  const int lane = tid & 63;
  const int w = tid >> 6;
  const int l5 = lane >> 5;
  const int lr32 = lane & 31;
  const int wm = w >> 1, wn = w & 1;

  const int nwg = gridDim.x;
  const int nb = (blockIdx.x & 7) * (nwg >> 3) + (blockIdx.x >> 3);
  const int m0 = (nb / gx) * BM;
  const int n0 = (nb % gx) * BN;

  f16v acc[2][2];
#pragma unroll
  for (int i = 0; i < 2; ++i)
#pragma unroll
    for (int j = 0; j < 2; ++j)
#pragma unroll
      for (int r = 0; r < 16; ++r) acc[i][j][r] = 0.f;

  const int NT = K >> 5;

  auto STAGE = [&](int t, int buf) {
    const int k0 = t << 5;
#pragma unroll
    for (int l = 0; l < 4; ++l) {
      const int cb = (l * 4 + w) * 64;
      const int ch = cb + lane;
      const ushort* src;
      if (ch < CHA) {
        const int row = ch >> 2;
        const int cs = (ch & 3) ^ ((row >> 1) & 3);
        src = A + (size_t)(m0 + row) * K + k0 + cs * 8;
      } else {
        const int c2 = ch - CHA;
        const int row = c2 >> 2;
        const int cs = (c2 & 3) ^ ((row >> 1) & 3);
        src = B + (size_t)(n0 + row) * K + k0 + cs * 8;
      }
      GLDS16(src, lds + buf * TILEB + cb * 16);
    }
  };

  STAGE(0, 0);
  STAGE(1, 1);
  wait_vmcnt<4>();
  BAR;

  int bufc = 0;
  for (int t = 0; t < NT; ++t) {
    const bool more = (t + 2) < NT;
    if (more) STAGE(t + 2, bufc == 0 ? 2 : (bufc == 1 ? 0 : 1));

    const char* bb = lds + bufc * TILEB;
#pragma unroll
    for (int ks = 0; ks < 2; ++ks) {
      sh8 a[2], b[2];
#pragma unroll
      for (int mt = 0; mt < 2; ++mt) {
        const int row = wm * 64 + mt * 32 + lr32;
        a[mt] = *(const sh8*)(bb + row * 64 + (((ks * 2 + l5) ^ ((row >> 1) & 3)) * 16));
      }
#pragma unroll
      for (int nt = 0; nt < 2; ++nt) {
        const int row = wn * 64 + nt * 32 + lr32;
        b[nt] = *(const sh8*)(bb + BM * 64 + row * 64 + (((ks * 2 + l5) ^ ((row >> 1) & 3)) * 16));
      }
      __builtin_amdgcn_s_setprio(1);
#pragma unroll
      for (int mt = 0; mt < 2; ++mt)
#pragma unroll
        for (int nt = 0; nt < 2; ++nt)
          acc[mt][nt] = __builtin_amdgcn_mfma_f32_32x32x16_bf16(a[mt], b[nt], acc[mt][nt], 0, 0, 0);
      __builtin_amdgcn_s_setprio(0);
    }

    if (more) wait_vmcnt<4>();
    else      wait_vmcnt<0>();
    BAR;
    bufc = bufc == 2 ? 0 : bufc + 1;
  }

#pragma unroll
  for (int mt = 0; mt < 2; ++mt)
#pragma unroll
    for (int nt = 0; nt < 2; ++nt) {
      const int gcol = n0 + wn * 64 + nt * 32 + lr32;
#pragma unroll
      for (int r = 0; r < 16; ++r) {
        const int grow = m0 + wm * 64 + mt * 32 + (r & 3) + 8 * (r >> 2) + 4 * l5;
        __builtin_nontemporal_store(acc[mt][nt][r], &C[(size_t)grow * N + gcol]);
      }
    }
}

// ---------------- fused RMSNorm + rotary + V-mix (4 (t,h) pairs / block) ----------------
__global__ __launch_bounds__(256) void k_fuse(const ushort* __restrict__ qkvb,
                                              const float* __restrict__ ve,
                                              const float* __restrict__ lam,
                                              ushort* __restrict__ qh, ushort* __restrict__ kh,
                                              ushort* __restrict__ vh) {
  const int pair = blockIdx.x * 4 + (threadIdx.x >> 6);
  const int t = pair >> 3, h = pair & 7;
  const int l = threadIdx.x & 63;
  const ushort* base = qkvb + (size_t)t * NQKV + h * HDIM + 2 * l;
  uint qu = *reinterpret_cast<const uint*>(base);
  uint ku = *reinterpret_cast<const uint*>(base + 1024);
  uint vu = *reinterpret_cast<const uint*>(base + 2048);
  float q0 = bf2f((ushort)qu), q1 = bf2f((ushort)(qu >> 16));
  float k0 = bf2f((ushort)ku), k1 = bf2f((ushort)(ku >> 16));
  float v0 = bf2f((ushort)vu), v1 = bf2f((ushort)(vu >> 16));
  float sq = q0 * q0 + q1 * q1, sk = k0 * k0 + k1 * k1;
#pragma unroll
  for (int m = 1; m < 64; m <<= 1) { sq += __shfl_xor(sq, m); sk += __shfl_xor(sk, m); }
  const float eps = 1.1920928955078125e-07f;
  float rq = rsqrtf(sq * (1.f / 128.f) + eps);
  float rk = rsqrtf(sk * (1.f / 128.f) + eps);
  q0 *= rq; q1 *= rq; k0 *= rk; k1 *= rk;
  float c0 = 1.f, s0 = 0.f, c1 = 1.f, s1 = 0.f;
  if ((l & 31) < 16) {
    const int f0 = 2 * (l & 31);
    float fr0 = exp2f(-10.f * (float)f0 * (1.f / 31.f));
    float fr1 = exp2f(-10.f * (float)(f0 + 1) * (1.f / 31.f));
    sincosf((float)t * fr0, &s0, &c0);
    sincosf((float)t * fr1, &s1, &c1);
  }
  float qx0 = __shfl_xor(q0, 32), qx1 = __shfl_xor(q1, 32);
  float kx0 = __shfl_xor(k0, 32), kx1 = __shfl_xor(k1, 32);
  const float sgn = (l < 32) ? 1.f : -1.f;
  float qr0 = q0 * c0 + sgn * qx0 * s0;
  float qr1 = q1 * c1 + sgn * qx1 * s1;
  float kr0 = k0 * c0 + sgn * kx0 * s0;
  float kr1 = k1 * c1 + sgn * kx1 * s1;
  const float l0 = lam[0], l1 = lam[1];
  float2 vev = *reinterpret_cast<const float2*>(ve + (size_t)t * DIMN + h * HDIM + 2 * l);
  float vr0 = l0 * v0 + l1 * vev.x;
  float vr1 = l0 * v1 + l1 * vev.y;
  const size_t o = ((size_t)h * T_SEQ + t) * HDIM + 2 * l;
  *reinterpret_cast<uint*>(qh + o) = (uint)f2bf(qr0) | ((uint)f2bf(qr1) << 16);
  *reinterpret_cast<uint*>(kh + o) = (uint)f2bf(kr0) | ((uint)f2bf(kr1) << 16);
  *reinterpret_cast<uint*>(vh + o) = (uint)f2bf(vr0) | ((uint)f2bf(vr1) << 16);
}

// ---------------- V transpose: vh[h][t][d] -> vt[h][d][t] ----------------
__global__ __launch_bounds__(256) void k_vt(const ushort* __restrict__ vh, ushort* __restrict__ vt) {
  const int tb = blockIdx.x, db = blockIdx.y, h = blockIdx.z;
  __shared__ ushort L[64][68];
  const int tid = threadIdx.x;
  const int t0 = tb * 64, d0 = db * 64;
  const size_t ib = ((size_t)h * T_SEQ + t0) * HDIM + d0;
#pragma unroll
  for (int p = 0; p < 4; ++p) {
    const int row = p * 16 + (tid >> 4);
    const int c4 = (tid & 15) * 4;
    ushort4 v = *reinterpret_cast<const ushort4*>(vh + ib + (size_t)row * HDIM + c4);
    *reinterpret_cast<ushort4*>(&L[row][c4]) = v;
  }
  __syncthreads();
  const size_t ob = ((size_t)h * HDIM + d0) * T_SEQ + t0;
#pragma unroll
  for (int p = 0; p < 4; ++p) {
    const int drow = p * 16 + (tid >> 4);
    const int t4 = (tid & 15) * 4;
    ushort4 v;
    v.x = L[t4 + 0][drow]; v.y = L[t4 + 1][drow];
    v.z = L[t4 + 2][drow]; v.w = L[t4 + 3][drow];
    *reinterpret_cast<ushort4*>(vt + ob + (size_t)drow * T_SEQ + t4) = v;
  }
}

// ---------------- flash attention: 4 waves, 64 q-rows, LDS-staged KV ----------------
__global__ __launch_bounds__(256) void k_attn(const ushort* __restrict__ qh,
                                              const ushort* __restrict__ kh,
                                              const ushort* __restrict__ vt,
                                              const int* __restrict__ doc_start,
                                              ushort* __restrict__ y) {
  const int h  = blockIdx.x;
  const int qb = blockIdx.y;
  const int q0 = qb * 64;
  const int tid  = threadIdx.x;
  const int wave = tid >> 6;
  const int lane = tid & 63;
  const int lr = lane & 15, lg = lane >> 4;

  __shared__ ushort Ks[2][64 * 128];
  __shared__ ushort Vs[2][128 * 64];
  __shared__ ushort Ps[4][16 * 64];

  const ushort* Kg = kh + (size_t)h * T_SEQ * HDIM;
  const ushort* Vg = vt + (size_t)h * HDIM * T_SEQ;

  const int i_me = q0 + wave * 16 + lr;
  sh8 qf[4];
  {
    const ushort* qp = qh + ((size_t)h * T_SEQ + i_me) * HDIM + lg * 8;
#pragma unroll
    for (int c = 0; c < 4; ++c) qf[c] = *reinterpret_cast<const sh8*>(qp + c * 32);
  }
  const int ds_me = doc_start[i_me];
  const int ds_hi = doc_start[q0 + 63];
  const int kb0   = doc_start[q0] >> 6;

  const f4 fzero = {0.f, 0.f, 0.f, 0.f};
  f4 o_acc[8];
#pragma unroll
  for (int i = 0; i < 8; ++i) o_acc[i] = fzero;
  float m_me = -1e30f, l_me = 0.f;

  auto STAGE = [&](int b, int k0) {
#pragma unroll
    for (int p = 0; p < 4; ++p) {
      const int c = p * 256 + tid;
      const int row = c >> 4, cc = c & 15;
      GLDS16(Kg + (size_t)(k0 + row) * HDIM + (cc ^ (row & 7)) * 8,
             &Ks[b][(p * 256 + wave * 64) * 8]);
    }
#pragma unroll
    for (int p = 0; p < 4; ++p) {
      const int c = p * 256 + tid;
      const int d = c >> 3, cc = c & 7;
      GLDS16(Vg + (size_t)d * T_SEQ + k0 + (cc ^ (d & 7)) * 8,
             &Vs[b][(p * 256 + wave * 64) * 8]);
    }
  };

  int cur = 0;
  STAGE(0, kb0 * 64);

  const int sw = (lr & 7) << 4;

  for (int kb = kb0; kb <= qb; ++kb) {
    const int k0 = kb * 64;
    __syncthreads();
    if (kb < qb) STAGE(cur ^ 1, k0 + 64);

    const char* Kb = (const char*)&Ks[cur][0];
    const char* Vb = (const char*)&Vs[cur][0];
    char* Pw = (char*)&Ps[wave][0];

    f4 sacc[4];
#pragma unroll
    for (int jt = 0; jt < 4; ++jt) sacc[jt] = fzero;
#pragma unroll
    for (int jt = 0; jt < 4; ++jt)
#pragma unroll
      for (int c = 0; c < 4; ++c) {
        sh8 kf = *reinterpret_cast<const sh8*>(Kb + (jt * 16 + lr) * 256 + ((c * 64 + lg * 16) ^ sw));
        sacc[jt] = __builtin_amdgcn_mfma_f32_16x16x32_bf16(kf, qf[c], sacc[jt], 0, 0, 0);
      }

    const bool fullblk = (kb < qb) && (ds_hi <= k0);
    float p[4][4];
#pragma unroll
    for (int jt = 0; jt < 4; ++jt)
#pragma unroll
      for (int r = 0; r < 4; ++r) {
        float s = sacc[jt][r] * ATTN_SCALE;
        const int j = k0 + jt * 16 + lg * 4 + r;
        bool valid = fullblk || ((j <= i_me) && (j >= ds_me));
        p[jt][r] = valid ? s : -1e30f;
      }
    float tm = -1e30f;
#pragma unroll
    for (int jt = 0; jt < 4; ++jt) {
      float a = fmaxf(p[jt][0], p[jt][1]), b = fmaxf(p[jt][2], p[jt][3]);
      tm = fmaxf(tm, fmaxf(a, b));
    }
    tm = fmaxf(tm, __shfl_xor(tm, 16));
    tm = fmaxf(tm, __shfl_xor(tm, 32));
    const float mnew = fmaxf(m_me, tm);
    const float sc = __expf(m_me - mnew);
    m_me = mnew;
    float rs = 0.f;
#pragma unroll
    for (int jt = 0; jt < 4; ++jt)
#pragma unroll
      for (int r = 0; r < 4; ++r) {
        float pv = __expf(p[jt][r] - mnew);
        p[jt][r] = pv;
        rs += pv;
      }
    rs += __shfl_xor(rs, 16);
    rs += __shfl_xor(rs, 32);
    l_me = l_me * sc + rs;

#pragma unroll
    for (int jt = 0; jt < 4; ++jt) {
      uint2 u;
      u.x = (uint)f2bf(p[jt][0]) | ((uint)f2bf(p[jt][1]) << 16);
      u.y = (uint)f2bf(p[jt][2]) | ((uint)f2bf(p[jt][3]) << 16);
      *reinterpret_cast<uint2*>(Pw + lr * 128 + ((jt * 32 + lg * 8) ^ sw)) = u;
    }

    float sco[4];
#pragma unroll
    for (int rr = 0; rr < 4; ++rr) sco[rr] = __shfl(sc, lg * 4 + rr);
#pragma unroll
    for (int dt = 0; dt < 8; ++dt)
#pragma unroll
      for (int rr = 0; rr < 4; ++rr) o_acc[dt][rr] *= sco[rr];

#pragma unroll
    for (int ks = 0; ks < 2; ++ks) {
      sh8 pa = *reinterpret_cast<const sh8*>(Pw + lr * 128 + ((ks * 64 + lg * 16) ^ sw));
#pragma unroll
      for (int dt = 0; dt < 8; ++dt) {
        sh8 vf = *reinterpret_cast<const sh8*>(Vb + (dt * 16 + lr) * 128 + ((ks * 64 + lg * 16) ^ sw));
        o_acc[dt] = __builtin_amdgcn_mfma_f32_16x16x32_bf16(pa, vf, o_acc[dt], 0, 0, 0);
      }
    }

    __builtin_amdgcn_s_barrier();
    cur ^= 1;
  }

  float lo[4];
#pragma unroll
  for (int rr = 0; rr < 4; ++rr) lo[rr] = __shfl(l_me, lg * 4 + rr);
#pragma unroll
  for (int dt = 0; dt < 8; ++dt)
#pragma unroll
    for (int rr = 0; rr < 4; ++rr) {
      const int trow = q0 + wave * 16 + lg * 4 + rr;
      y[(size_t)trow * DIMN + h * HDIM + dt * 16 + lr] = f2bf(o_acc[dt][rr] / lo[rr]);
    }
}

extern "C" void kernel_launch(void* const* d_in, const int* in_sizes, int n_in,
                              void* d_out, int out_size, void* d_ws, size_t ws_size,
                              hipStream_t stream) {
  const float* x    = (const float*)d_in[0];
  const float* ve   = (const float*)d_in[1];
  const float* qkvw = (const float*)d_in[2];
  const float* lam  = (const float*)d_in[3];
  const float* cpw  = (const float*)d_in[4];
  const int*   docs = (const int*)d_in[5];
  float* out = (float*)d_out;
  char* ws = (char*)d_ws;

  ushort* qkvb = (ushort*)(ws);                    // 24MB  [0,24)
  ushort* xb   = (ushort*)(ws + (24ull << 20));    // 8MB   [24,32)
  ushort* wb   = (ushort*)(ws + (32ull << 20));    // 6MB   [32,38)
  ushort* cb   = (ushort*)(ws + (38ull << 20));    // 2MB   [38,40)
  ushort* qh   = (ushort*)(ws + (40ull << 20));    // 8MB   [40,48)
  ushort* kh   = (ushort*)(ws + (48ull << 20));    // 8MB   [48,56)
  ushort* vh   = (ushort*)(ws + (56ull << 20));    // 8MB   [56,64)
  ushort* vt   = (ushort*)(ws + (64ull << 20));    // 8MB   [64,72)
  ushort* yb   = (ushort*)(ws + (72ull << 20));    // 8MB   [72,80)
  int*  dstart = (int*)(ws + (80ull << 20));       // 16KB

  k_prep<<<8192 + 16, 256, 0, stream>>>(x, qkvw, cpw, xb, wb, cb, docs, dstart);

  // QKV: M=4096, N=3072, K=1024 — 128x384 tiles, grid 32x8 = 256 = 1/CU
  k_gemm32<<<256, 512, 0, stream>>>(xb, wb, qkvb, NQKV, DIMN);

  k_fuse<<<T_SEQ * NH / 4, 256, 0, stream>>>(qkvb, ve, lam, qh, kh, vh);
  k_vt<<<dim3(T_SEQ / 64, HDIM / 64, NH), 256, 0, stream>>>(vh, vt);

  k_attn<<<dim3(NH, T_SEQ / 64), 256, 0, stream>>>(qh, kh, vt, dstart, yb);

  // proj: M=4096, N=1024, K=1024 — 128x128 tile, grid 32x8=256 (%8==0)
  k_gemm2<<<256, 256, 0, stream>>>(yb, cb, out, DIMN, DIMN, DIMN / 128);
}